// Round 2
// baseline (489.509 us; speedup 1.0000x reference)
//
#include <hip/hip_runtime.h>
#include <hip/hip_bf16.h>
#include <math.h>

// Problem constants (fixed by setup_inputs): N=2048, D=512, K=65536
#define N_ROWS 2048
#define D_DIM  512
#define K_NEG  65536
#define INV_T  5.0f   // 1/0.2
#define NC     4      // colBlocks processed per block (epilogue amortization)

typedef __bf16 bf16x8 __attribute__((ext_vector_type(8)));
typedef float  f32x4  __attribute__((ext_vector_type(4)));

__device__ __forceinline__ void gload_lds16(const __bf16* g, __bf16* l) {
    __builtin_amdgcn_global_load_lds(
        (const __attribute__((address_space(1))) void*)g,
        (__attribute__((address_space(3))) void*)l, 16, 0, 0);
}

// ---------------------------------------------------------------------------
// Kernel 1: query/keys -> Abf (bf16), sq = 5/||q||, lpos (exact fp32),
//           rowsum init = exp(lpos).  One wave per row, 4 rows/block.
// ---------------------------------------------------------------------------
__global__ __launch_bounds__(256) void prep_qk_kernel(
    const float* __restrict__ query, const float* __restrict__ keys,
    __bf16* __restrict__ Abf, float* __restrict__ sq,
    float* __restrict__ lpos, float* __restrict__ rowsum) {
    const int lane = threadIdx.x & 63;
    const int row  = blockIdx.x * 4 + (threadIdx.x >> 6);
    const float4* qv = reinterpret_cast<const float4*>(query + (size_t)row * D_DIM) + lane * 2;
    const float4* kv = reinterpret_cast<const float4*>(keys  + (size_t)row * D_DIM) + lane * 2;
    float4 q0 = qv[0], q1 = qv[1];
    float4 k0 = kv[0], k1 = kv[1];
    float ssq = q0.x*q0.x + q0.y*q0.y + q0.z*q0.z + q0.w*q0.w
              + q1.x*q1.x + q1.y*q1.y + q1.z*q1.z + q1.w*q1.w;
    float ssk = k0.x*k0.x + k0.y*k0.y + k0.z*k0.z + k0.w*k0.w
              + k1.x*k1.x + k1.y*k1.y + k1.z*k1.z + k1.w*k1.w;
    float dot = q0.x*k0.x + q0.y*k0.y + q0.z*k0.z + q0.w*k0.w
              + q1.x*k1.x + q1.y*k1.y + q1.z*k1.z + q1.w*k1.w;
#pragma unroll
    for (int off = 32; off > 0; off >>= 1) {
        ssq += __shfl_xor(ssq, off, 64);
        ssk += __shfl_xor(ssk, off, 64);
        dot += __shfl_xor(dot, off, 64);
    }
    bf16x8 o;
    o[0] = (__bf16)q0.x; o[1] = (__bf16)q0.y; o[2] = (__bf16)q0.z; o[3] = (__bf16)q0.w;
    o[4] = (__bf16)q1.x; o[5] = (__bf16)q1.y; o[6] = (__bf16)q1.z; o[7] = (__bf16)q1.w;
    reinterpret_cast<bf16x8*>(Abf + (size_t)row * D_DIM)[lane] = o;
    if (lane == 0) {
        float qn = sqrtf(ssq), kn = sqrtf(ssk);
        float lp = dot / fmaxf(qn * kn, 1e-8f) * INV_T;
        sq[row]     = INV_T / fmaxf(qn, 1e-8f);
        lpos[row]   = lp;
        rowsum[row] = __expf(lp);   // positive-logit term; also inits accumulator
    }
}

// ---------------------------------------------------------------------------
// Kernel 2: queue -> Bbf (bf16), ru = 1/||u||.  One wave per row.
// ---------------------------------------------------------------------------
__global__ __launch_bounds__(256) void prep_queue_kernel(
    const float* __restrict__ queue, __bf16* __restrict__ Bbf,
    float* __restrict__ ru) {
    const int lane = threadIdx.x & 63;
    const int row  = blockIdx.x * 4 + (threadIdx.x >> 6);
    const float4* uv = reinterpret_cast<const float4*>(queue + (size_t)row * D_DIM) + lane * 2;
    float4 u0 = uv[0], u1 = uv[1];
    float ss = u0.x*u0.x + u0.y*u0.y + u0.z*u0.z + u0.w*u0.w
             + u1.x*u1.x + u1.y*u1.y + u1.z*u1.z + u1.w*u1.w;
#pragma unroll
    for (int off = 32; off > 0; off >>= 1) ss += __shfl_xor(ss, off, 64);
    bf16x8 o;
    o[0] = (__bf16)u0.x; o[1] = (__bf16)u0.y; o[2] = (__bf16)u0.z; o[3] = (__bf16)u0.w;
    o[4] = (__bf16)u1.x; o[5] = (__bf16)u1.y; o[6] = (__bf16)u1.z; o[7] = (__bf16)u1.w;
    reinterpret_cast<bf16x8*>(Bbf + (size_t)row * D_DIM)[lane] = o;
    if (lane == 0) ru[row] = 1.0f / fmaxf(sqrtf(ss), 1e-8f);
}

// ---------------------------------------------------------------------------
// Kernel 3: NT-GEMM with fused exp-rowsum.
// 128x128 tile, BK=32, 4 waves (2x2), 4x4 frags of 16x16x32 bf16 MFMA.
// Round-2 changes:
//  - XOR-swizzled LDS layout (applied on the global SOURCE address, since
//    global_load_lds dest is uniform-base+lane*16): stored 16B chunk
//    slot c holds global chunk g = c ^ ((row>>1)&3).  Read-side bank start
//    = 16*(m16&1) + 4*(q4^((m16>>1)&3)) -> 2-way max (free).
//  - NC=4 colBlocks per block; per-row exp-sums accumulated in registers,
//    shuffle+atomic epilogue once per block (was per colBlock).
//  - XCD-aware 1D grid: xcd = i&7 pins each colGroup's 16 rowBlocks to one
//    XCD so the 512KB B-slab is fetched once into that XCD's L2.
// ---------------------------------------------------------------------------
__global__ __launch_bounds__(256, 3) void gemm_exp_kernel(
    const __bf16* __restrict__ A, const __bf16* __restrict__ B,
    const float* __restrict__ sq, const float* __restrict__ ru,
    float* __restrict__ rowsum) {
    __shared__ __bf16 sA[128 * 32];
    __shared__ __bf16 sB[128 * 32];
    const int tid  = threadIdx.x;
    const int wave = tid >> 6, lane = tid & 63;

    // XCD-aware decode: 2048 blocks = 8 xcd * 16 colGroupLocal * 16 rowBlock
    const int bi  = blockIdx.x;
    const int xcd = bi & 7;
    const int j9  = bi >> 3;             // 0..255
    const int colGroup = xcd * 16 + (j9 >> 4);   // 0..127 -> 4 colBlocks each
    const int rowBlock = j9 & 15;

    const int wm = wave >> 1, wn = wave & 1;
    const int q4 = lane >> 4, m16 = lane & 15;

    // staging: chunk j covers tile rows [16j,16j+16); wave w does j=w, j=w+4.
    // lane = r4*4 + c2; LDS slot (r4,c2) <- global chunk g = c2 ^ ((r4>>1)&3)
    const int r4 = lane >> 2, c2 = lane & 3;
    const int gsw = c2 ^ ((r4 >> 1) & 3);
    const int j0 = wave, j1 = wave + 4;
    const __bf16* gA = A + (((size_t)(rowBlock * 128 + r4)) << 9) + (gsw << 3);

    // per-row exp-sum accumulators, persist across the NC colBlocks
    float srow[4][4] = {{0.f,0.f,0.f,0.f},{0.f,0.f,0.f,0.f},
                        {0.f,0.f,0.f,0.f},{0.f,0.f,0.f,0.f}};

    for (int c = 0; c < NC; ++c) {
        const int colBlock = colGroup * NC + c;
        const __bf16* gB = B + (((size_t)(colBlock * 128 + r4)) << 9) + (gsw << 3);

        f32x4 acc[4][4] = {};

        for (int kt = 0; kt < D_DIM / 32; ++kt) {
            const int kof = kt * 32;
            gload_lds16(gA + (size_t)j0 * 16 * D_DIM + kof, &sA[j0 * 512]);
            gload_lds16(gA + (size_t)j1 * 16 * D_DIM + kof, &sA[j1 * 512]);
            gload_lds16(gB + (size_t)j0 * 16 * D_DIM + kof, &sB[j0 * 512]);
            gload_lds16(gB + (size_t)j1 * 16 * D_DIM + kof, &sB[j1 * 512]);
            __syncthreads();

            bf16x8 af[4], bq[4];
            const int rsw = (q4 ^ ((m16 >> 1) & 3)) << 3;  // swizzled chunk offset
#pragma unroll
            for (int i = 0; i < 4; ++i)
                af[i] = *reinterpret_cast<const bf16x8*>(&sA[(wm * 64 + i * 16 + m16) * 32 + rsw]);
#pragma unroll
            for (int j = 0; j < 4; ++j)
                bq[j] = *reinterpret_cast<const bf16x8*>(&sB[(wn * 64 + j * 16 + m16) * 32 + rsw]);
#pragma unroll
            for (int i = 0; i < 4; ++i)
#pragma unroll
                for (int j = 0; j < 4; ++j)
                    acc[i][j] = __builtin_amdgcn_mfma_f32_16x16x32_bf16(af[i], bq[j], acc[i][j], 0, 0, 0);
            __syncthreads();
        }

        // per-colBlock epilogue: exp and accumulate into srow registers
        float ruv[4];
#pragma unroll
        for (int j = 0; j < 4; ++j)
            ruv[j] = ru[colBlock * 128 + wn * 64 + j * 16 + m16];
#pragma unroll
        for (int i = 0; i < 4; ++i) {
#pragma unroll
            for (int r = 0; r < 4; ++r) {
                const int grow = rowBlock * 128 + wm * 64 + i * 16 + q4 * 4 + r;
                const float sqv = sq[grow];
                float s = 0.f;
#pragma unroll
                for (int j = 0; j < 4; ++j)
                    s += __expf(acc[i][j][r] * sqv * ruv[j]);
                srow[i][r] += s;
            }
        }
    }

    // one shuffle-reduce + atomic per row per block (was NC of each)
#pragma unroll
    for (int i = 0; i < 4; ++i) {
#pragma unroll
        for (int r = 0; r < 4; ++r) {
            float s = srow[i][r];
#pragma unroll
            for (int off = 1; off < 16; off <<= 1)
                s += __shfl_xor(s, off, 64);
            if (m16 == 0) {
                const int grow = rowBlock * 128 + wm * 64 + i * 16 + q4 * 4 + r;
                atomicAdd(&rowsum[grow], s);
            }
        }
    }
}

// ---------------------------------------------------------------------------
// Kernel 4: loss = mean(log(rowsum) - lpos)
// ---------------------------------------------------------------------------
__global__ __launch_bounds__(256) void finalize_kernel(
    const float* __restrict__ rowsum, const float* __restrict__ lpos,
    float* __restrict__ out) {
    const int tid = threadIdx.x;
    float acc = 0.f;
    for (int n = tid; n < N_ROWS; n += 256)
        acc += __logf(rowsum[n]) - lpos[n];
#pragma unroll
    for (int off = 32; off > 0; off >>= 1) acc += __shfl_xor(acc, off, 64);
    __shared__ float red[4];
    if ((tid & 63) == 0) red[tid >> 6] = acc;
    __syncthreads();
    if (tid == 0) out[0] = (red[0] + red[1] + red[2] + red[3]) * (1.0f / (float)N_ROWS);
}

extern "C" void kernel_launch(void* const* d_in, const int* in_sizes, int n_in,
                              void* d_out, int out_size, void* d_ws, size_t ws_size,
                              hipStream_t stream) {
    const float* query = (const float*)d_in[0];
    const float* keys  = (const float*)d_in[1];
    const float* queue = (const float*)d_in[2];

    char* ws = (char*)d_ws;
    __bf16* Abf = (__bf16*)ws;  ws += (size_t)N_ROWS * D_DIM * sizeof(__bf16);   // 2 MB
    __bf16* Bbf = (__bf16*)ws;  ws += (size_t)K_NEG  * D_DIM * sizeof(__bf16);   // 64 MB
    float*  sq   = (float*)ws;  ws += (size_t)N_ROWS * sizeof(float);
    float*  ru   = (float*)ws;  ws += (size_t)K_NEG  * sizeof(float);
    float*  lpos = (float*)ws;  ws += (size_t)N_ROWS * sizeof(float);
    float*  rsum = (float*)ws;  ws += (size_t)N_ROWS * sizeof(float);

    prep_qk_kernel<<<N_ROWS / 4, 256, 0, stream>>>(query, keys, Abf, sq, lpos, rsum);
    prep_queue_kernel<<<K_NEG / 4, 256, 0, stream>>>(queue, Bbf, ru);
    // 2048 blocks = 16 rowBlocks x 128 colGroups (x NC=4 colBlocks inside)
    gemm_exp_kernel<<<(N_ROWS / 128) * (K_NEG / 128 / NC), 256, 0, stream>>>(Abf, Bbf, sq, ru, rsum);
    finalize_kernel<<<1, 256, 0, stream>>>(rsum, lpos, (float*)d_out);
}

// Round 3
// 383.803 us; speedup vs baseline: 1.2754x; 1.2754x over previous
//
#include <hip/hip_runtime.h>
#include <hip/hip_bf16.h>
#include <math.h>

// Problem constants (fixed by setup_inputs): N=2048, D=512, K=65536
#define N_ROWS 2048
#define D_DIM  512
#define K_NEG  65536
#define INV_T  5.0f   // 1/0.2
#define NC     4      // colBlocks processed per block (epilogue amortization)
#define NT     (NC * 16)   // flat pipeline iterations: NC colBlocks x 16 kt

typedef __bf16 bf16x8 __attribute__((ext_vector_type(8)));
typedef float  f32x4  __attribute__((ext_vector_type(4)));

__device__ __forceinline__ void gload_lds16(const __bf16* g, __bf16* l) {
    __builtin_amdgcn_global_load_lds(
        (const __attribute__((address_space(1))) void*)g,
        (__attribute__((address_space(3))) void*)l, 16, 0, 0);
}

// ---------------------------------------------------------------------------
// Kernel 1 (merged preps): one wave per row, 4 rows/block.
//  blocks [0, 512):          query/keys -> Abf, sq=5/||q||, lpos, rowsum=exp(lpos)
//  blocks [512, 512+16384):  queue -> Bbf, ru=1/||u||
// ---------------------------------------------------------------------------
__global__ __launch_bounds__(256) void prep_all_kernel(
    const float* __restrict__ query, const float* __restrict__ keys,
    const float* __restrict__ queue,
    __bf16* __restrict__ Abf, __bf16* __restrict__ Bbf,
    float* __restrict__ sq, float* __restrict__ ru,
    float* __restrict__ lpos, float* __restrict__ rowsum) {
    const int lane = threadIdx.x & 63;
    if (blockIdx.x < N_ROWS / 4) {
        const int row = blockIdx.x * 4 + (threadIdx.x >> 6);
        const float4* qv = reinterpret_cast<const float4*>(query + (size_t)row * D_DIM) + lane * 2;
        const float4* kv = reinterpret_cast<const float4*>(keys  + (size_t)row * D_DIM) + lane * 2;
        float4 q0 = qv[0], q1 = qv[1];
        float4 k0 = kv[0], k1 = kv[1];
        float ssq = q0.x*q0.x + q0.y*q0.y + q0.z*q0.z + q0.w*q0.w
                  + q1.x*q1.x + q1.y*q1.y + q1.z*q1.z + q1.w*q1.w;
        float ssk = k0.x*k0.x + k0.y*k0.y + k0.z*k0.z + k0.w*k0.w
                  + k1.x*k1.x + k1.y*k1.y + k1.z*k1.z + k1.w*k1.w;
        float dot = q0.x*k0.x + q0.y*k0.y + q0.z*k0.z + q0.w*k0.w
                  + q1.x*k1.x + q1.y*k1.y + q1.z*k1.z + q1.w*k1.w;
#pragma unroll
        for (int off = 32; off > 0; off >>= 1) {
            ssq += __shfl_xor(ssq, off, 64);
            ssk += __shfl_xor(ssk, off, 64);
            dot += __shfl_xor(dot, off, 64);
        }
        bf16x8 o;
        o[0] = (__bf16)q0.x; o[1] = (__bf16)q0.y; o[2] = (__bf16)q0.z; o[3] = (__bf16)q0.w;
        o[4] = (__bf16)q1.x; o[5] = (__bf16)q1.y; o[6] = (__bf16)q1.z; o[7] = (__bf16)q1.w;
        reinterpret_cast<bf16x8*>(Abf + (size_t)row * D_DIM)[lane] = o;
        if (lane == 0) {
            float qn = sqrtf(ssq), kn = sqrtf(ssk);
            float lp = dot / fmaxf(qn * kn, 1e-8f) * INV_T;
            sq[row]     = INV_T / fmaxf(qn, 1e-8f);
            lpos[row]   = lp;
            rowsum[row] = __expf(lp);   // positive-logit term; also inits accumulator
        }
    } else {
        const int row = (blockIdx.x - N_ROWS / 4) * 4 + (threadIdx.x >> 6);
        const float4* uv = reinterpret_cast<const float4*>(queue + (size_t)row * D_DIM) + lane * 2;
        float4 u0 = uv[0], u1 = uv[1];
        float ss = u0.x*u0.x + u0.y*u0.y + u0.z*u0.z + u0.w*u0.w
                 + u1.x*u1.x + u1.y*u1.y + u1.z*u1.z + u1.w*u1.w;
#pragma unroll
        for (int off = 32; off > 0; off >>= 1) ss += __shfl_xor(ss, off, 64);
        bf16x8 o;
        o[0] = (__bf16)u0.x; o[1] = (__bf16)u0.y; o[2] = (__bf16)u0.z; o[3] = (__bf16)u0.w;
        o[4] = (__bf16)u1.x; o[5] = (__bf16)u1.y; o[6] = (__bf16)u1.z; o[7] = (__bf16)u1.w;
        reinterpret_cast<bf16x8*>(Bbf + (size_t)row * D_DIM)[lane] = o;
        if (lane == 0) ru[row] = 1.0f / fmaxf(sqrtf(ss), 1e-8f);
    }
}

// ---------------------------------------------------------------------------
// Kernel 2: NT-GEMM with fused exp-rowsum.
// 128x128 tile, BK=32, 4 waves (2x2), 4x4 frags of 16x16x32 bf16 MFMA.
// Round-3 structure: SINGLE-barrier double-buffered pipeline over a flat
// t-loop (NC colBlocks x 16 kt).  Per iter:
//   barrier  (drains loads(t), issued one full MFMA stage ago)
//   issue loads(t+1) -> buf^1     (overlaps with this iter's compute)
//   ds_read buf + 16 MFMA
// This removes the m97 issue->drain adjacency that exposed full L3 latency.
// LDS source-address XOR swizzle kept (bank conflicts measured 0).
// Grid reverted to rowBlock-fastest (round-1 ordering; XCD decode regressed).
// ---------------------------------------------------------------------------
__global__ __launch_bounds__(256, 3) void gemm_exp_kernel(
    const __bf16* __restrict__ A, const __bf16* __restrict__ B,
    const float* __restrict__ sq, const float* __restrict__ ru,
    float* __restrict__ rowsum) {
    __shared__ __bf16 sA[2 * 4096];
    __shared__ __bf16 sB[2 * 4096];
    const int tid  = threadIdx.x;
    const int wave = tid >> 6, lane = tid & 63;
    const int rowBlock = blockIdx.x;   // 0..15  (fastest -> B-tile temporal locality)
    const int colGroup = blockIdx.y;   // 0..127 (NC=4 colBlocks each)

    const int wm = wave >> 1, wn = wave & 1;
    const int q4 = lane >> 4, m16 = lane & 15;

    // staging lane map: lane = r4*4 + c2; LDS slot (r4,c2) <- global chunk
    // g = c2 ^ ((r4>>1)&3)  (source-address swizzle; dest is uniform+lane*16)
    const int r4 = lane >> 2, c2 = lane & 3;
    const int gsw = c2 ^ ((r4 >> 1) & 3);
    const int j0 = wave, j1 = wave + 4;          // 16-row chunks this wave stages
    const __bf16* gA  = A + (((size_t)(rowBlock * 128 + r4)) << 9) + (gsw << 3);
    const __bf16* gB0 = B + (((size_t)(colGroup * NC * 128 + r4)) << 9) + (gsw << 3);
    const int rsw = (q4 ^ ((m16 >> 1) & 3)) << 3;   // read-side swizzled chunk offset

    // hoisted row scales (same rows for every colBlock)
    float sqv[4][4];
#pragma unroll
    for (int i = 0; i < 4; ++i)
#pragma unroll
        for (int r = 0; r < 4; ++r)
            sqv[i][r] = sq[rowBlock * 128 + wm * 64 + i * 16 + q4 * 4 + r];

    float srow[4][4] = {{0.f,0.f,0.f,0.f},{0.f,0.f,0.f,0.f},
                        {0.f,0.f,0.f,0.f},{0.f,0.f,0.f,0.f}};
    f32x4 acc[4][4] = {};

    // stage(t, bufsel): issue 4 global_load_lds for iteration t
#define STAGE(T, BUF) do {                                                        \
        const int cb_ = (T) >> 4, kof_ = ((T) & 15) * 32;                         \
        const __bf16* gBc_ = gB0 + ((size_t)cb_ << 16);                           \
        __bf16* dA_ = &sA[(BUF) * 4096];                                          \
        __bf16* dB_ = &sB[(BUF) * 4096];                                          \
        gload_lds16(gA  + (size_t)j0 * 16 * D_DIM + kof_, &dA_[j0 * 512]);        \
        gload_lds16(gA  + (size_t)j1 * 16 * D_DIM + kof_, &dA_[j1 * 512]);        \
        gload_lds16(gBc_ + (size_t)j0 * 16 * D_DIM + kof_, &dB_[j0 * 512]);       \
        gload_lds16(gBc_ + (size_t)j1 * 16 * D_DIM + kof_, &dB_[j1 * 512]);       \
    } while (0)

    STAGE(0, 0);

    for (int t = 0; t < NT; ++t) {
        const int cur = t & 1;
        __syncthreads();                  // drains loads(t) (one stage in flight)
        if (t + 1 < NT) STAGE(t + 1, cur ^ 1);

        const __bf16* bA = &sA[cur * 4096];
        const __bf16* bB = &sB[cur * 4096];
        bf16x8 af[4], bq[4];
#pragma unroll
        for (int i = 0; i < 4; ++i)
            af[i] = *reinterpret_cast<const bf16x8*>(&bA[(wm * 64 + i * 16 + m16) * 32 + rsw]);
#pragma unroll
        for (int j = 0; j < 4; ++j)
            bq[j] = *reinterpret_cast<const bf16x8*>(&bB[(wn * 64 + j * 16 + m16) * 32 + rsw]);
#pragma unroll
        for (int i = 0; i < 4; ++i)
#pragma unroll
            for (int j = 0; j < 4; ++j)
                acc[i][j] = __builtin_amdgcn_mfma_f32_16x16x32_bf16(af[i], bq[j], acc[i][j], 0, 0, 0);

        if ((t & 15) == 15) {             // colBlock done: exp-accumulate, reset acc
            const int colBlock = colGroup * NC + (t >> 4);
            float ruv[4];
#pragma unroll
            for (int j = 0; j < 4; ++j)
                ruv[j] = ru[colBlock * 128 + wn * 64 + j * 16 + m16];
#pragma unroll
            for (int i = 0; i < 4; ++i)
#pragma unroll
                for (int r = 0; r < 4; ++r) {
                    float s = 0.f;
#pragma unroll
                    for (int j = 0; j < 4; ++j)
                        s += __expf(acc[i][j][r] * sqv[i][r] * ruv[j]);
                    srow[i][r] += s;
                    acc[i][0][r] = 0.f; acc[i][1][r] = 0.f;
                    acc[i][2][r] = 0.f; acc[i][3][r] = 0.f;
                }
        }
    }
#undef STAGE

    // one shuffle-reduce + atomic per row per block
#pragma unroll
    for (int i = 0; i < 4; ++i)
#pragma unroll
        for (int r = 0; r < 4; ++r) {
            float s = srow[i][r];
#pragma unroll
            for (int off = 1; off < 16; off <<= 1)
                s += __shfl_xor(s, off, 64);
            if (m16 == 0) {
                const int grow = rowBlock * 128 + wm * 64 + i * 16 + q4 * 4 + r;
                atomicAdd(&rowsum[grow], s);
            }
        }
}

// ---------------------------------------------------------------------------
// Kernel 3: loss = mean(log(rowsum) - lpos)
// ---------------------------------------------------------------------------
__global__ __launch_bounds__(256) void finalize_kernel(
    const float* __restrict__ rowsum, const float* __restrict__ lpos,
    float* __restrict__ out) {
    const int tid = threadIdx.x;
    float acc = 0.f;
    for (int n = tid; n < N_ROWS; n += 256)
        acc += __logf(rowsum[n]) - lpos[n];
#pragma unroll
    for (int off = 32; off > 0; off >>= 1) acc += __shfl_xor(acc, off, 64);
    __shared__ float red[4];
    if ((tid & 63) == 0) red[tid >> 6] = acc;
    __syncthreads();
    if (tid == 0) out[0] = (red[0] + red[1] + red[2] + red[3]) * (1.0f / (float)N_ROWS);
}

extern "C" void kernel_launch(void* const* d_in, const int* in_sizes, int n_in,
                              void* d_out, int out_size, void* d_ws, size_t ws_size,
                              hipStream_t stream) {
    const float* query = (const float*)d_in[0];
    const float* keys  = (const float*)d_in[1];
    const float* queue = (const float*)d_in[2];

    char* ws = (char*)d_ws;
    __bf16* Abf = (__bf16*)ws;  ws += (size_t)N_ROWS * D_DIM * sizeof(__bf16);   // 2 MB
    __bf16* Bbf = (__bf16*)ws;  ws += (size_t)K_NEG  * D_DIM * sizeof(__bf16);   // 64 MB
    float*  sq   = (float*)ws;  ws += (size_t)N_ROWS * sizeof(float);
    float*  ru   = (float*)ws;  ws += (size_t)K_NEG  * sizeof(float);
    float*  lpos = (float*)ws;  ws += (size_t)N_ROWS * sizeof(float);
    float*  rsum = (float*)ws;  ws += (size_t)N_ROWS * sizeof(float);

    prep_all_kernel<<<N_ROWS / 4 + K_NEG / 4, 256, 0, stream>>>(
        query, keys, queue, Abf, Bbf, sq, ru, lpos, rsum);
    gemm_exp_kernel<<<dim3(N_ROWS / 128, K_NEG / 128 / NC), 256, 0, stream>>>(
        Abf, Bbf, sq, ru, rsum);
    finalize_kernel<<<1, 256, 0, stream>>>(rsum, lpos, (float*)d_out);
}